// Round 6
// baseline (295.181 us; speedup 1.0000x reference)
//
#include <hip/hip_runtime.h>
#include <hip/hip_bf16.h>

#define NPG 9
#define DH 64
#define DIN 11
#define GPB 16                  // graphs (= 16-row tiles) per block
#define TPW 4                   // tiles per wave
#define TPB 256                 // 4 waves
#define NGRAPH 65536
#define NBLK (NGRAPH/GPB)       // 4096, exact
#define XTOT (NGRAPH*NPG*DIN)   // 6488064 floats in x
#define OUT_HALF ((long long)NGRAPH*8)

typedef __attribute__((ext_vector_type(8))) short short8;
typedef __attribute__((ext_vector_type(4))) float f32x4;

// weight staging, rewritten by prep_kernel every launch
__device__ float g_c1[DH];          // folded conv1 bias: b1 + (root+8*rel)@b_in
__device__ short g_bfrag1[8*512];   // conv1 B-frags: f 0..3 = Wa (y), 4..7 = Wb (u); K=32 (rows>=16 zero)
__device__ short g_bfrag2[16*512];  // conv2 B-frags: K=128 = [M2 | rel2]
__device__ short g_bfragH[2*512];   // head B-frags: K=64, N=16

__device__ __forceinline__ short f2bs(float f) {
  __hip_bfloat16 h = __float2bfloat16(f);
  return __builtin_bit_cast(short, h);
}
__device__ __forceinline__ float fast_tanh(float v) {
  float e = __expf(2.f*v);
  return 1.f - 2.f*__builtin_amdgcn_rcpf(e + 1.f);
}

// Fragment convention (16x16x32 bf16), HW-verified rounds 1-3:
//   A[row = l&15][k = (l>>4)*8 + j],  B[k = (l>>4)*8 + j][n = nt*16 + (l&15)]
//   C/D: col = l&15, row = (l>>4)*4 + reg
__global__ void prep_kernel(const float* __restrict__ W_in, const float* __restrict__ b_in,
                            const float* __restrict__ W1_rel, const float* __restrict__ b1,
                            const float* __restrict__ W1_root,
                            const float* __restrict__ W2_rel, const float* __restrict__ W2_root,
                            const float* __restrict__ W_head) {
  const int blk = blockIdx.x, tid = threadIdx.x;
  if (blk < 2) {
    // conv1 frags: Wa = (root-rel)@W_in, Wb = rel@W_in, computed per element
    for (int i = blk*256 + tid; i < 8*512; i += 512) {
      int f = i >> 9, l = (i >> 3) & 63, j = i & 7;
      int k = ((l >> 4) << 3) + j;                 // 0..31
      int n = ((f & 3) << 4) + (l & 15);           // 0..63
      float v = 0.f;
      if (k < DIN) {
        for (int m = 0; m < DH; ++m) {
          float wi = W_in[m*DIN + k];
          float r  = W1_rel[n*DH + m];
          v += ((f < 4) ? (W1_root[n*DH + m] - r) : r) * wi;
        }
      }
      g_bfrag1[i] = f2bs(v);
    }
  } else if (blk < 10) {
    for (int i = (blk - 2)*256 + tid; i < 16*512; i += 2048) {
      int frag = i >> 9, kk = frag >> 2;
      int l = (i >> 3) & 63, j = i & 7;
      int k2 = kk*32 + ((l >> 4) << 3) + j;        // 0..127
      int n  = (frag & 3)*16 + (l & 15);
      float v = (k2 < 64) ? (W2_root[n*DH + k2] - W2_rel[n*DH + k2])
                          : W2_rel[n*DH + k2 - 64];
      g_bfrag2[i] = f2bs(v);
    }
  } else if (blk == 10) {
    for (int i = tid; i < 2*512; i += 256) {
      int kk = i >> 9;
      int l = (i >> 3) & 63, j = i & 7;
      int k = kk*32 + ((l >> 4) << 3) + j;         // 0..63
      int n = l & 15;                              // p = n>>1, oc = n&1
      g_bfragH[i] = f2bs(W_head[(n >> 1)*(DH*2) + k*2 + (n & 1)]);
    }
  } else {
    if (tid < DH) {
      float c = b1[tid];
      for (int m = 0; m < DH; ++m)
        c += (W1_root[tid*DH + m] + 8.f*W1_rel[tid*DH + m]) * b_in[m];
      g_c1[tid] = c;
    }
  }
}

__global__ __launch_bounds__(TPB, 4) void fused_kernel(
    const float* __restrict__ x,
    const float* __restrict__ b2,
    const float* __restrict__ bhead,
    float* __restrict__ out)
{
  // Hs: [256 rows][64 cols] bf16, 16B-chunk XOR swizzle by (row&7)
  __shared__ short Hs[256*64];     // 32768 B
  __shared__ short Ss[GPB*64];     // 2048 B  (per-graph tanh-h sums)

  const int tid  = threadIdx.x;
  const int lane = tid & 63;
  const int wave = tid >> 6;       // 0..3
  const int l15  = lane & 15;
  const int kgrp = lane >> 4;      // 0..3
  const int ksel = kgrp & 1;
  const int t0   = wave*TPW;                       // first tile of this wave
  const unsigned gg0 = (unsigned)blockIdx.x*GPB + t0;  // first graph of this wave

  // ================= conv1: z1 = tanh(x@Wa^T + (Sx@Wb^T) + c1) =================
  {
    short8 By[4], Bu[4];
    #pragma unroll
    for (int nt = 0; nt < 4; ++nt) {
      By[nt] = *(const short8*)&g_bfrag1[nt*512 + lane*8];
      Bu[nt] = *(const short8*)&g_bfrag1[(4 + nt)*512 + lane*8];
    }
    float c1v[4];
    #pragma unroll
    for (int nt = 0; nt < 4; ++nt) c1v[nt] = g_c1[nt*16 + l15];

    // direct-global x fragment loads, per-element bounds guard.
    // BUGFIX (r5): the old 8-wide clamp (off = min(off, XTOT-8)) rewound the
    // last node's ksel=1 lanes so cols 3..5 landed where cols 8..10 belong.
    // OOB elements here are exactly the slots masked to 0 in A below.
    float xr[TPW][8];
    #pragma unroll
    for (int i = 0; i < TPW; ++i) {
      const unsigned base = ((gg0 + i)*NPG + l15)*DIN + ksel*8;
      #pragma unroll
      for (int j = 0; j < 8; ++j) {
        const unsigned e = base + j;
        xr[i][j] = (e < (unsigned)XTOT) ? x[e] : 0.f;
      }
    }

    const bool real = (l15 <= 8);       // A-layout row = l15; rows 9..15 are pad
    #pragma unroll
    for (int i = 0; i < TPW; ++i) {
      const int T = t0 + i;
      short8 A;
      #pragma unroll
      for (int j = 0; j < 8; ++j) {
        // ksel==1 lanes carry cols 8..10 only; pad rows zeroed so the u
        // column sums are exact
        bool ok = real && (ksel == 0 || j < 3);
        A[j] = ok ? f2bs(xr[i][j]) : (short)0;
      }
      f32x4 y[4], u[4];
      #pragma unroll
      for (int nt = 0; nt < 4; ++nt) { y[nt] = (f32x4){0,0,0,0}; u[nt] = (f32x4){0,0,0,0}; }
      #pragma unroll
      for (int nt = 0; nt < 4; ++nt) {
        y[nt] = __builtin_amdgcn_mfma_f32_16x16x32_bf16(A, By[nt], y[nt], 0, 0, 0);
        u[nt] = __builtin_amdgcn_mfma_f32_16x16x32_bf16(A, Bu[nt], u[nt], 0, 0, 0);
      }
      // column-sum u within the tile (pad rows contribute exact 0) -> Sx@Wb^T
      float suc[4];
      #pragma unroll
      for (int nt = 0; nt < 4; ++nt) {
        float s = (u[nt][0] + u[nt][1]) + (u[nt][2] + u[nt][3]);
        s += __shfl_xor(s, 16);
        s += __shfl_xor(s, 32);
        suc[nt] = s + c1v[nt];
      }
      // epilogue: tanh, zero pad rows, store swizzled bf16, accumulate S_h
      float sh[4];
      #pragma unroll
      for (int nt = 0; nt < 4; ++nt) {
        float acc = 0.f;
        #pragma unroll
        for (int reg = 0; reg < 4; ++reg) {
          const int row = kgrp*4 + reg;          // C-layout row within tile
          float v = fast_tanh(y[nt][reg] + suc[nt]);
          v = (row <= 8) ? v : 0.f;
          acc += v;
          const int rr  = T*16 + row;
          const int col = nt*16 + l15;
          Hs[rr*64 + ((((col >> 3) ^ (row & 7))) << 3) + (col & 7)] = f2bs(v);
        }
        sh[nt] = acc;
      }
      #pragma unroll
      for (int nt = 0; nt < 4; ++nt) {
        float s = sh[nt];
        s += __shfl_xor(s, 16);
        s += __shfl_xor(s, 32);
        if (kgrp == 0) Ss[T*64 + nt*16 + l15] = f2bs(s);
      }
    }
  }

  // ================= conv2: z2 = tanh([h|S] @ [M2;rel2]^T + b2) =================
  {
    short8 B2[4][4];
    #pragma unroll
    for (int kk = 0; kk < 4; ++kk)
      #pragma unroll
      for (int nt = 0; nt < 4; ++nt)
        B2[kk][nt] = *(const short8*)&g_bfrag2[(kk*4 + nt)*512 + lane*8];
    float b2v[4];
    #pragma unroll
    for (int nt = 0; nt < 4; ++nt) b2v[nt] = b2[nt*16 + l15];

    #pragma unroll
    for (int i = 0; i < TPW; ++i) {
      const int T = t0 + i;
      const int row = T*16 + l15;
      short8 A0 = *(const short8*)&Hs[row*64 + (((0 + kgrp) ^ (l15 & 7)) << 3)];
      short8 A1 = *(const short8*)&Hs[row*64 + (((4 + kgrp) ^ (l15 & 7)) << 3)];
      short8 A2 = *(const short8*)&Ss[T*64 + kgrp*8];        // broadcast reads
      short8 A3 = *(const short8*)&Ss[T*64 + 32 + kgrp*8];
      f32x4 acc[4];
      #pragma unroll
      for (int nt = 0; nt < 4; ++nt)
        acc[nt] = (f32x4){b2v[nt], b2v[nt], b2v[nt], b2v[nt]};
      #pragma unroll
      for (int nt = 0; nt < 4; ++nt) {
        acc[nt] = __builtin_amdgcn_mfma_f32_16x16x32_bf16(A0, B2[0][nt], acc[nt], 0, 0, 0);
        acc[nt] = __builtin_amdgcn_mfma_f32_16x16x32_bf16(A1, B2[1][nt], acc[nt], 0, 0, 0);
        acc[nt] = __builtin_amdgcn_mfma_f32_16x16x32_bf16(A2, B2[2][nt], acc[nt], 0, 0, 0);
        acc[nt] = __builtin_amdgcn_mfma_f32_16x16x32_bf16(A3, B2[3][nt], acc[nt], 0, 0, 0);
      }
      #pragma unroll
      for (int nt = 0; nt < 4; ++nt) {
        #pragma unroll
        for (int reg = 0; reg < 4; ++reg) {
          const int row2 = kgrp*4 + reg;
          float v = fast_tanh(acc[nt][reg]);
          v = (row2 <= 8) ? v : 0.f;
          const int rr  = T*16 + row2;
          const int col = nt*16 + l15;
          Hs[rr*64 + ((((col >> 3) ^ (row2 & 7))) << 3) + (col & 7)] = f2bs(v);
        }
      }
    }
  }

  // ================= head: per-graph [16x64]@[64x16], scatter stores =================
  {
    short8 H0 = *(const short8*)&g_bfragH[lane*8];
    short8 H1 = *(const short8*)&g_bfragH[512 + lane*8];
    const int p  = l15 >> 1;
    const int oc = l15 & 1;
    const float bh = bhead[l15];                 // = bhead[p*2 + oc]
    const int trow = p + 1;                      // head reads node p+1
    const bool mykg = ((trow >> 2) == kgrp);
    const int treg = trow & 3;

    #pragma unroll
    for (int i = 0; i < TPW; ++i) {
      const int T = t0 + i;
      const int row = T*16 + l15;
      short8 A0 = *(const short8*)&Hs[row*64 + (((0 + kgrp) ^ (l15 & 7)) << 3)];
      short8 A1 = *(const short8*)&Hs[row*64 + (((4 + kgrp) ^ (l15 & 7)) << 3)];
      f32x4 acc = (f32x4){bh, bh, bh, bh};
      acc = __builtin_amdgcn_mfma_f32_16x16x32_bf16(A0, H0, acc, 0, 0, 0);
      acc = __builtin_amdgcn_mfma_f32_16x16x32_bf16(A1, H1, acc, 0, 0, 0);
      float val = (treg & 2) ? ((treg & 1) ? acc[3] : acc[2])
                             : ((treg & 1) ? acc[1] : acc[0]);
      float tv = val + 0.5413248546129181f;      // log(expm1(1))
      float e  = __expf(tv);
      float sp = (tv > 15.f) ? tv : __logf(1.f + e);
      sp = fmaxf(sp, 1e-4f);
      float res = oc ? sp : val;
      if (mykg) {
        const long long gg = (long long)blockIdx.x*GPB + T;
        out[(oc ? OUT_HALF : 0) + gg*8 + p] = res;
      }
    }
  }
}

extern "C" void kernel_launch(void* const* d_in, const int* in_sizes, int n_in,
                              void* d_out, int out_size, void* d_ws, size_t ws_size,
                              hipStream_t stream) {
  const float* x       = (const float*)d_in[0];
  // d_in[1] = edge_index: full 9-clique structure is compile-time, unused
  const float* W_in    = (const float*)d_in[2];
  const float* b_in    = (const float*)d_in[3];
  const float* W1_rel  = (const float*)d_in[4];
  const float* b1      = (const float*)d_in[5];
  const float* W1_root = (const float*)d_in[6];
  const float* W2_rel  = (const float*)d_in[7];
  const float* b2      = (const float*)d_in[8];
  const float* W2_root = (const float*)d_in[9];
  const float* Whead   = (const float*)d_in[10];
  const float* bhead   = (const float*)d_in[11];
  float* out = (float*)d_out;

  hipLaunchKernelGGL(prep_kernel, dim3(12), dim3(256), 0, stream,
                     W_in, b_in, W1_rel, b1, W1_root, W2_rel, W2_root, Whead);
  hipLaunchKernelGGL(fused_kernel, dim3(NBLK), dim3(TPB), 0, stream,
                     x, b2, bhead, out);
}

// Round 8
// 214.180 us; speedup vs baseline: 1.3782x; 1.3782x over previous
//
#include <hip/hip_runtime.h>
#include <hip/hip_bf16.h>

#define NPG 9
#define DH 64
#define DIN 11
#define GPB 16                  // graphs (= 16-row tiles) per block
#define TPW 4                   // tiles per wave
#define TPB 256                 // 4 waves
#define NGRAPH 65536
#define NBLK (NGRAPH/GPB)       // 4096, exact
#define XTOT (NGRAPH*NPG*DIN)   // 6488064 floats in x
#define OUT_HALF ((long long)NGRAPH*8)

typedef __attribute__((ext_vector_type(8))) short short8;
typedef __attribute__((ext_vector_type(4))) float f32x4;

// weight staging, rewritten by prep_kernel every launch
__device__ float g_c1[DH];          // folded conv1 bias: b1 + (root+8*rel)@b_in
__device__ short g_bfrag1[8*512];   // conv1 B-frags: f 0..3 = Wa (y), 4..7 = Wb (u); K=32 (rows>=16 zero)
__device__ short g_bfrag2[16*512];  // conv2 B-frags: K=128 = [M2 | rel2]
__device__ short g_bfragH[2*512];   // head B-frags: K=64, N=16

__device__ __forceinline__ short f2bs(float f) {
  __hip_bfloat16 h = __float2bfloat16(f);
  return __builtin_bit_cast(short, h);
}
__device__ __forceinline__ float fast_tanh(float v) {
  float e = __expf(2.f*v);
  return 1.f - 2.f*__builtin_amdgcn_rcpf(e + 1.f);
}

// Fragment convention (16x16x32 bf16), HW-verified rounds 1-3:
//   A[row = l&15][k = (l>>4)*8 + j],  B[k = (l>>4)*8 + j][n = nt*16 + (l&15)]
//   C/D: col = l&15, row = (l>>4)*4 + reg
__global__ void prep_kernel(const float* __restrict__ W_in, const float* __restrict__ b_in,
                            const float* __restrict__ W1_rel, const float* __restrict__ b1,
                            const float* __restrict__ W1_root,
                            const float* __restrict__ W2_rel, const float* __restrict__ W2_root,
                            const float* __restrict__ W_head) {
  const int blk = blockIdx.x, tid = threadIdx.x;
  if (blk < 2) {
    // conv1 frags: Wa = (root-rel)@W_in, Wb = rel@W_in, computed per element
    for (int i = blk*256 + tid; i < 8*512; i += 512) {
      int f = i >> 9, l = (i >> 3) & 63, j = i & 7;
      int k = ((l >> 4) << 3) + j;                 // 0..31
      int n = ((f & 3) << 4) + (l & 15);           // 0..63
      float v = 0.f;
      if (k < DIN) {
        for (int m = 0; m < DH; ++m) {
          float wi = W_in[m*DIN + k];
          float r  = W1_rel[n*DH + m];
          v += ((f < 4) ? (W1_root[n*DH + m] - r) : r) * wi;
        }
      }
      g_bfrag1[i] = f2bs(v);
    }
  } else if (blk < 10) {
    for (int i = (blk - 2)*256 + tid; i < 16*512; i += 2048) {
      int frag = i >> 9, kk = frag >> 2;
      int l = (i >> 3) & 63, j = i & 7;
      int k2 = kk*32 + ((l >> 4) << 3) + j;        // 0..127
      int n  = (frag & 3)*16 + (l & 15);
      float v = (k2 < 64) ? (W2_root[n*DH + k2] - W2_rel[n*DH + k2])
                          : W2_rel[n*DH + k2 - 64];
      g_bfrag2[i] = f2bs(v);
    }
  } else if (blk == 10) {
    for (int i = tid; i < 2*512; i += 256) {
      int kk = i >> 9;
      int l = (i >> 3) & 63, j = i & 7;
      int k = kk*32 + ((l >> 4) << 3) + j;         // 0..63
      int n = l & 15;                              // p = n>>1, oc = n&1
      g_bfragH[i] = f2bs(W_head[(n >> 1)*(DH*2) + k*2 + (n & 1)]);
    }
  } else {
    if (tid < DH) {
      float c = b1[tid];
      for (int m = 0; m < DH; ++m)
        c += (W1_root[tid*DH + m] + 8.f*W1_rel[tid*DH + m]) * b_in[m];
      g_c1[tid] = c;
    }
  }
}

// launch_bounds (256, 2): 2 waves/EU min -> 256 unified VGPR+AGPR cap.
// r6 post-mortem: (256,4) capped regs at 128, spilling ~65 regs/thread ->
// 282 MB scratch writes + ~130 MB scratch reads per dispatch (WRITE_SIZE
// counter vs 4.2 MB of real output). Spill-free > occupancy here.
__global__ __launch_bounds__(TPB, 2) void fused_kernel(
    const float* __restrict__ x,
    const float* __restrict__ b2,
    const float* __restrict__ bhead,
    float* __restrict__ out)
{
  // Hs: [256 rows][64 cols] bf16, 16B-chunk XOR swizzle by (row&7)
  __shared__ short Hs[256*64];     // 32768 B
  __shared__ short Ss[GPB*64];     // 2048 B  (per-graph tanh-h sums)

  const int tid  = threadIdx.x;
  const int lane = tid & 63;
  const int wave = tid >> 6;       // 0..3
  const int l15  = lane & 15;
  const int kgrp = lane >> 4;      // 0..3
  const int ksel = kgrp & 1;
  const int t0   = wave*TPW;                       // first tile of this wave
  const unsigned gg0 = (unsigned)blockIdx.x*GPB + t0;  // first graph of this wave

  // ================= conv1: z1 = tanh(x@Wa^T + (Sx@Wb^T) + c1) =================
  {
    short8 By[4], Bu[4];
    #pragma unroll
    for (int nt = 0; nt < 4; ++nt) {
      By[nt] = *(const short8*)&g_bfrag1[nt*512 + lane*8];
      Bu[nt] = *(const short8*)&g_bfrag1[(4 + nt)*512 + lane*8];
    }
    float c1v[4];
    #pragma unroll
    for (int nt = 0; nt < 4; ++nt) c1v[nt] = g_c1[nt*16 + l15];

    // direct-global x fragment loads. Fast path: whole 8-wide slab in bounds
    // (all blocks except the very last node region). Slow path keeps the r5
    // per-element guard: OOB slots are exactly the slots masked to 0 in A.
    float xr[TPW][8];
    #pragma unroll
    for (int i = 0; i < TPW; ++i) {
      const unsigned base = ((gg0 + i)*NPG + l15)*DIN + ksel*8;
      if (base + 8 <= (unsigned)XTOT) {
        #pragma unroll
        for (int j = 0; j < 8; ++j) xr[i][j] = x[base + j];
      } else {
        #pragma unroll
        for (int j = 0; j < 8; ++j) {
          const unsigned e = base + j;
          xr[i][j] = (e < (unsigned)XTOT) ? x[e] : 0.f;
        }
      }
    }

    const bool real = (l15 <= 8);       // A-layout row = l15; rows 9..15 are pad
    #pragma unroll
    for (int i = 0; i < TPW; ++i) {
      const int T = t0 + i;
      short8 A;
      #pragma unroll
      for (int j = 0; j < 8; ++j) {
        // ksel==1 lanes carry cols 8..10 only; pad rows zeroed so the u
        // column sums are exact
        bool ok = real && (ksel == 0 || j < 3);
        A[j] = ok ? f2bs(xr[i][j]) : (short)0;
      }
      f32x4 y[4], u[4];
      #pragma unroll
      for (int nt = 0; nt < 4; ++nt) { y[nt] = (f32x4){0,0,0,0}; u[nt] = (f32x4){0,0,0,0}; }
      #pragma unroll
      for (int nt = 0; nt < 4; ++nt) {
        y[nt] = __builtin_amdgcn_mfma_f32_16x16x32_bf16(A, By[nt], y[nt], 0, 0, 0);
        u[nt] = __builtin_amdgcn_mfma_f32_16x16x32_bf16(A, Bu[nt], u[nt], 0, 0, 0);
      }
      // column-sum u within the tile (pad rows contribute exact 0) -> Sx@Wb^T
      float suc[4];
      #pragma unroll
      for (int nt = 0; nt < 4; ++nt) {
        float s = (u[nt][0] + u[nt][1]) + (u[nt][2] + u[nt][3]);
        s += __shfl_xor(s, 16);
        s += __shfl_xor(s, 32);
        suc[nt] = s + c1v[nt];
      }
      // epilogue: tanh, zero pad rows, store swizzled bf16, accumulate S_h
      float sh[4];
      #pragma unroll
      for (int nt = 0; nt < 4; ++nt) {
        float acc = 0.f;
        #pragma unroll
        for (int reg = 0; reg < 4; ++reg) {
          const int row = kgrp*4 + reg;          // C-layout row within tile
          float v = fast_tanh(y[nt][reg] + suc[nt]);
          v = (row <= 8) ? v : 0.f;
          acc += v;
          const int rr  = T*16 + row;
          const int col = nt*16 + l15;
          Hs[rr*64 + ((((col >> 3) ^ (row & 7))) << 3) + (col & 7)] = f2bs(v);
        }
        sh[nt] = acc;
      }
      #pragma unroll
      for (int nt = 0; nt < 4; ++nt) {
        float s = sh[nt];
        s += __shfl_xor(s, 16);
        s += __shfl_xor(s, 32);
        if (kgrp == 0) Ss[T*64 + nt*16 + l15] = f2bs(s);
      }
    }
  }

  // ================= conv2: z2 = tanh([h|S] @ [M2;rel2]^T + b2) =================
  {
    short8 B2[4][4];
    #pragma unroll
    for (int kk = 0; kk < 4; ++kk)
      #pragma unroll
      for (int nt = 0; nt < 4; ++nt)
        B2[kk][nt] = *(const short8*)&g_bfrag2[(kk*4 + nt)*512 + lane*8];
    float b2v[4];
    #pragma unroll
    for (int nt = 0; nt < 4; ++nt) b2v[nt] = b2[nt*16 + l15];

    #pragma unroll
    for (int i = 0; i < TPW; ++i) {
      const int T = t0 + i;
      const int row = T*16 + l15;
      short8 A0 = *(const short8*)&Hs[row*64 + (((0 + kgrp) ^ (l15 & 7)) << 3)];
      short8 A1 = *(const short8*)&Hs[row*64 + (((4 + kgrp) ^ (l15 & 7)) << 3)];
      short8 A2 = *(const short8*)&Ss[T*64 + kgrp*8];        // broadcast reads
      short8 A3 = *(const short8*)&Ss[T*64 + 32 + kgrp*8];
      f32x4 acc[4];
      #pragma unroll
      for (int nt = 0; nt < 4; ++nt)
        acc[nt] = (f32x4){b2v[nt], b2v[nt], b2v[nt], b2v[nt]};
      #pragma unroll
      for (int nt = 0; nt < 4; ++nt) {
        acc[nt] = __builtin_amdgcn_mfma_f32_16x16x32_bf16(A0, B2[0][nt], acc[nt], 0, 0, 0);
        acc[nt] = __builtin_amdgcn_mfma_f32_16x16x32_bf16(A1, B2[1][nt], acc[nt], 0, 0, 0);
        acc[nt] = __builtin_amdgcn_mfma_f32_16x16x32_bf16(A2, B2[2][nt], acc[nt], 0, 0, 0);
        acc[nt] = __builtin_amdgcn_mfma_f32_16x16x32_bf16(A3, B2[3][nt], acc[nt], 0, 0, 0);
      }
      #pragma unroll
      for (int nt = 0; nt < 4; ++nt) {
        #pragma unroll
        for (int reg = 0; reg < 4; ++reg) {
          const int row2 = kgrp*4 + reg;
          float v = fast_tanh(acc[nt][reg]);
          v = (row2 <= 8) ? v : 0.f;
          const int rr  = T*16 + row2;
          const int col = nt*16 + l15;
          Hs[rr*64 + ((((col >> 3) ^ (row2 & 7))) << 3) + (col & 7)] = f2bs(v);
        }
      }
    }
  }

  // ================= head: per-graph [16x64]@[64x16], scatter stores =================
  {
    short8 H0 = *(const short8*)&g_bfragH[lane*8];
    short8 H1 = *(const short8*)&g_bfragH[512 + lane*8];
    const int p  = l15 >> 1;
    const int oc = l15 & 1;
    const float bh = bhead[l15];                 // = bhead[p*2 + oc]
    const int trow = p + 1;                      // head reads node p+1
    const bool mykg = ((trow >> 2) == kgrp);
    const int treg = trow & 3;

    #pragma unroll
    for (int i = 0; i < TPW; ++i) {
      const int T = t0 + i;
      const int row = T*16 + l15;
      short8 A0 = *(const short8*)&Hs[row*64 + (((0 + kgrp) ^ (l15 & 7)) << 3)];
      short8 A1 = *(const short8*)&Hs[row*64 + (((4 + kgrp) ^ (l15 & 7)) << 3)];
      f32x4 acc = (f32x4){bh, bh, bh, bh};
      acc = __builtin_amdgcn_mfma_f32_16x16x32_bf16(A0, H0, acc, 0, 0, 0);
      acc = __builtin_amdgcn_mfma_f32_16x16x32_bf16(A1, H1, acc, 0, 0, 0);
      float val = (treg & 2) ? ((treg & 1) ? acc[3] : acc[2])
                             : ((treg & 1) ? acc[1] : acc[0]);
      float tv = val + 0.5413248546129181f;      // log(expm1(1))
      float e  = __expf(tv);
      float sp = (tv > 15.f) ? tv : __logf(1.f + e);
      sp = fmaxf(sp, 1e-4f);
      float res = oc ? sp : val;
      if (mykg) {
        const long long gg = (long long)blockIdx.x*GPB + T;
        out[(oc ? OUT_HALF : 0) + gg*8 + p] = res;
      }
    }
  }
}

extern "C" void kernel_launch(void* const* d_in, const int* in_sizes, int n_in,
                              void* d_out, int out_size, void* d_ws, size_t ws_size,
                              hipStream_t stream) {
  const float* x       = (const float*)d_in[0];
  // d_in[1] = edge_index: full 9-clique structure is compile-time, unused
  const float* W_in    = (const float*)d_in[2];
  const float* b_in    = (const float*)d_in[3];
  const float* W1_rel  = (const float*)d_in[4];
  const float* b1      = (const float*)d_in[5];
  const float* W1_root = (const float*)d_in[6];
  const float* W2_rel  = (const float*)d_in[7];
  const float* b2      = (const float*)d_in[8];
  const float* W2_root = (const float*)d_in[9];
  const float* Whead   = (const float*)d_in[10];
  const float* bhead   = (const float*)d_in[11];
  float* out = (float*)d_out;

  hipLaunchKernelGGL(prep_kernel, dim3(12), dim3(256), 0, stream,
                     W_in, b_in, W1_rel, b1, W1_root, W2_rel, W2_root, Whead);
  hipLaunchKernelGGL(fused_kernel, dim3(NBLK), dim3(TPB), 0, stream,
                     x, b2, bhead, out);
}

// Round 10
// 182.683 us; speedup vs baseline: 1.6158x; 1.1724x over previous
//
#include <hip/hip_runtime.h>
#include <hip/hip_bf16.h>

#define NPG 9
#define DH 64
#define DIN 11
#define GPB 8                   // graphs (= 16-row tiles) per block
#define TPW 2                   // tiles per wave
#define TPB 256                 // 4 waves
#define NGRAPH 65536
#define NBLK (NGRAPH/GPB)       // 8192, exact
#define XTOT (NGRAPH*NPG*DIN)   // 6488064 floats in x
#define OUT_HALF ((long long)NGRAPH*8)

typedef __attribute__((ext_vector_type(8))) short short8;
typedef __attribute__((ext_vector_type(4))) float f32x4;

// weight staging, rewritten by prep_kernel every launch
__device__ float g_c1[DH];          // folded conv1 bias: b1 + (root+8*rel)@b_in
__device__ short g_bfrag1[8*512];   // conv1 B-frags: f 0..3 = Wa (y), 4..7 = Wb (u); rows k>=11 zero
__device__ short g_bfrag2[16*512];  // conv2 B-frags: K=128 = [M2 | rel2]
__device__ short g_bfragH[2*512];   // head B-frags: K=64, N=16

__device__ __forceinline__ short f2bs(float f) {
  __hip_bfloat16 h = __float2bfloat16(f);
  return __builtin_bit_cast(short, h);
}
__device__ __forceinline__ float fast_tanh(float v) {
  float e = __expf(2.f*v);
  return 1.f - 2.f*__builtin_amdgcn_rcpf(e + 1.f);
}

// Fragment convention (16x16x32 bf16), HW-verified rounds 1-3:
//   A[row = l&15][k = (l>>4)*8 + j],  B[k = (l>>4)*8 + j][n = nt*16 + (l&15)]
//   C/D: col = l&15, row = (l>>4)*4 + reg
// prep r9: conv1-frag blocks stage W_in/W1_rel/W1_root in LDS (the 64-FMA
// inner loop was global-load latency-bound before); c1 parallelized 4x.
__global__ void prep_kernel(const float* __restrict__ W_in, const float* __restrict__ b_in,
                            const float* __restrict__ W1_rel, const float* __restrict__ b1,
                            const float* __restrict__ W1_root,
                            const float* __restrict__ W2_rel, const float* __restrict__ W2_root,
                            const float* __restrict__ W_head) {
  const int blk = blockIdx.x, tid = threadIdx.x;
  if (blk < 8) {
    // conv1 frags: Wa = (root-rel)@W_in, Wb = rel@W_in; 512 elements per block
    __shared__ float pw[704 + 4096 + 4096];
    for (int i = tid; i < 704 + 4096 + 4096; i += TPB) {
      float v;
      if (i < 704)       v = W_in[i];
      else if (i < 4800) v = W1_rel[i - 704];
      else               v = W1_root[i - 4800];
      pw[i] = v;
    }
    __syncthreads();
    #pragma unroll
    for (int e = 0; e < 2; ++e) {
      const int i = blk*512 + e*256 + tid;
      const int f = i >> 9, l = (i >> 3) & 63, j = i & 7;
      const int k = ((l >> 4) << 3) + j;             // 0..31
      const int n = ((f & 3) << 4) + (l & 15);       // 0..63
      float v = 0.f;
      if (k < DIN) {
        const float* __restrict__ rel = &pw[704  + n*64];
        const float* __restrict__ rt  = &pw[4800 + n*64];
        for (int m = 0; m < DH; ++m) {
          float wi = pw[m*DIN + k];
          v += ((f < 4) ? (rt[m] - rel[m]) : rel[m]) * wi;
        }
      }
      g_bfrag1[i] = f2bs(v);
    }
  } else if (blk < 16) {
    // conv2 frags: elementwise, 1024 per block
    #pragma unroll
    for (int e = 0; e < 4; ++e) {
      const int i = (blk - 8)*1024 + e*256 + tid;
      const int frag = i >> 9, kk = frag >> 2;
      const int l = (i >> 3) & 63, j = i & 7;
      const int k2 = kk*32 + ((l >> 4) << 3) + j;    // 0..127
      const int n  = (frag & 3)*16 + (l & 15);
      const float v = (k2 < 64) ? (W2_root[n*DH + k2] - W2_rel[n*DH + k2])
                                : W2_rel[n*DH + k2 - 64];
      g_bfrag2[i] = f2bs(v);
    }
  } else if (blk == 16) {
    for (int i = tid; i < 2*512; i += TPB) {
      const int kk = i >> 9;
      const int l = (i >> 3) & 63, j = i & 7;
      const int k = kk*32 + ((l >> 4) << 3) + j;     // 0..63
      const int n = l & 15;                          // p = n>>1, oc = n&1
      g_bfragH[i] = f2bs(W_head[(n >> 1)*(DH*2) + k*2 + (n & 1)]);
    }
  } else {
    // c1 = b1 + (root + 8*rel) @ b_in : 64 outputs x 4 partial threads
    const int n = tid >> 2, q = tid & 3;
    float s = 0.f;
    for (int m = q*16; m < q*16 + 16; ++m)
      s += (W1_root[n*DH + m] + 8.f*W1_rel[n*DH + m]) * b_in[m];
    s += __shfl_xor(s, 1);
    s += __shfl_xor(s, 2);
    if (q == 0) g_c1[n] = b1[n] + s;
  }
}

// launch_bounds (256,3): reg cap ~170. r8 lesson: (256,4)=128 cap spilled
// ~400 MB scratch; (256,2)=256 cap was spill-free but left occupancy at
// ~10 waves/CU. r9 cuts live regs (split-K conv2, TPW=2) to fit ~110-130,
// targeting ~16-18 waves/CU. WRITE_SIZE >> 4 MB next round = spill returned.
__global__ __launch_bounds__(TPB, 3) void fused_kernel(
    const float* __restrict__ x,
    const float* __restrict__ b2,
    const float* __restrict__ bhead,
    float* __restrict__ out)
{
  // Hs: [128 rows][64 cols] bf16, 16B-chunk XOR swizzle by (row&7)
  __shared__ short Hs[128*64];     // 16384 B
  __shared__ short Ss[GPB*64];     // 1024 B  (per-graph tanh-h sums)

  const int tid  = threadIdx.x;
  const int lane = tid & 63;
  const int wave = tid >> 6;       // 0..3
  const int l15  = lane & 15;
  const int kgrp = lane >> 4;      // 0..3
  const int ksel = kgrp & 1;
  const int t0   = wave*TPW;                           // first tile of this wave
  const unsigned gg0 = (unsigned)blockIdx.x*GPB + t0;  // first graph of this wave

  // ================= conv1: z1 = tanh(x@Wa^T + (Sx@Wb^T) + c1) =================
  {
    short8 By[4], Bu[4];
    #pragma unroll
    for (int nt = 0; nt < 4; ++nt) {
      By[nt] = *(const short8*)&g_bfrag1[nt*512 + lane*8];
      Bu[nt] = *(const short8*)&g_bfrag1[(4 + nt)*512 + lane*8];
    }
    float c1v[4];
    #pragma unroll
    for (int nt = 0; nt < 4; ++nt) c1v[nt] = g_c1[nt*16 + l15];

    // direct-global x fragment loads. Fast path: whole 8-wide slab in bounds.
    // Slow path keeps the r5 per-element guard: OOB slots are exactly the
    // slots masked to 0 in A below.
    float xr[TPW][8];
    #pragma unroll
    for (int i = 0; i < TPW; ++i) {
      const unsigned base = ((gg0 + i)*NPG + l15)*DIN + ksel*8;
      if (base + 8 <= (unsigned)XTOT) {
        #pragma unroll
        for (int j = 0; j < 8; ++j) xr[i][j] = x[base + j];
      } else {
        #pragma unroll
        for (int j = 0; j < 8; ++j) {
          const unsigned e = base + j;
          xr[i][j] = (e < (unsigned)XTOT) ? x[e] : 0.f;
        }
      }
    }

    const bool real = (l15 <= 8);       // A-layout row = l15; rows 9..15 are pad
    #pragma unroll
    for (int i = 0; i < TPW; ++i) {
      const int T = t0 + i;
      short8 A;
      #pragma unroll
      for (int j = 0; j < 8; ++j) {
        // ksel==1 lanes carry cols 8..10 only; pad rows zeroed so the u
        // column sums are exact. (B rows k>=11 are zero, so kgrp>=2 content
        // is harmless as long as it is finite.)
        bool ok = real && (ksel == 0 || j < 3);
        A[j] = ok ? f2bs(xr[i][j]) : (short)0;
      }
      f32x4 y[4], u[4];
      #pragma unroll
      for (int nt = 0; nt < 4; ++nt) { y[nt] = (f32x4){0,0,0,0}; u[nt] = (f32x4){0,0,0,0}; }
      #pragma unroll
      for (int nt = 0; nt < 4; ++nt) {
        y[nt] = __builtin_amdgcn_mfma_f32_16x16x32_bf16(A, By[nt], y[nt], 0, 0, 0);
        u[nt] = __builtin_amdgcn_mfma_f32_16x16x32_bf16(A, Bu[nt], u[nt], 0, 0, 0);
      }
      // column-sum u within the tile (pad rows contribute exact 0) -> Sx@Wb^T
      float suc[4];
      #pragma unroll
      for (int nt = 0; nt < 4; ++nt) {
        float s = (u[nt][0] + u[nt][1]) + (u[nt][2] + u[nt][3]);
        s += __shfl_xor(s, 16);
        s += __shfl_xor(s, 32);
        suc[nt] = s + c1v[nt];
      }
      // epilogue: tanh, zero pad rows, store swizzled bf16, accumulate S_h
      float sh[4];
      #pragma unroll
      for (int nt = 0; nt < 4; ++nt) {
        float acc = 0.f;
        #pragma unroll
        for (int reg = 0; reg < 4; ++reg) {
          const int row = kgrp*4 + reg;          // C-layout row within tile
          float v = fast_tanh(y[nt][reg] + suc[nt]);
          v = (row <= 8) ? v : 0.f;
          acc += v;
          const int rr  = T*16 + row;
          const int col = nt*16 + l15;
          Hs[rr*64 + ((((col >> 3) ^ (row & 7))) << 3) + (col & 7)] = f2bs(v);
        }
        sh[nt] = acc;
      }
      #pragma unroll
      for (int nt = 0; nt < 4; ++nt) {
        float s = sh[nt];
        s += __shfl_xor(s, 16);
        s += __shfl_xor(s, 32);
        if (kgrp == 0) Ss[T*64 + nt*16 + l15] = f2bs(s);
      }
    }
  }

  // ========== conv2: z2 = tanh([h|S] @ [M2;rel2]^T + b2), split-K halves ==========
  {
    float b2v[4];
    #pragma unroll
    for (int nt = 0; nt < 4; ++nt) b2v[nt] = b2[nt*16 + l15];
    f32x4 acc[TPW][4];
    #pragma unroll
    for (int i = 0; i < TPW; ++i)
      #pragma unroll
      for (int nt = 0; nt < 4; ++nt)
        acc[i][nt] = (f32x4){b2v[nt], b2v[nt], b2v[nt], b2v[nt]};

    // half 0: K 0..63 (h from Hs); half 1: K 64..127 (S from Ss).
    // Only one 32-reg B-frag half is live at a time (r8: 64 live).
    #pragma unroll
    for (int h = 0; h < 2; ++h) {
      short8 Bh[2][4];
      #pragma unroll
      for (int kk = 0; kk < 2; ++kk)
        #pragma unroll
        for (int nt = 0; nt < 4; ++nt)
          Bh[kk][nt] = *(const short8*)&g_bfrag2[((h*2 + kk)*4 + nt)*512 + lane*8];
      #pragma unroll
      for (int i = 0; i < TPW; ++i) {
        const int T = t0 + i;
        short8 Aa, Ab;
        if (h == 0) {
          const int row = T*16 + l15;
          Aa = *(const short8*)&Hs[row*64 + (((0 + kgrp) ^ (l15 & 7)) << 3)];
          Ab = *(const short8*)&Hs[row*64 + (((4 + kgrp) ^ (l15 & 7)) << 3)];
        } else {
          Aa = *(const short8*)&Ss[T*64 + kgrp*8];        // broadcast reads
          Ab = *(const short8*)&Ss[T*64 + 32 + kgrp*8];
        }
        #pragma unroll
        for (int nt = 0; nt < 4; ++nt) {
          acc[i][nt] = __builtin_amdgcn_mfma_f32_16x16x32_bf16(Aa, Bh[0][nt], acc[i][nt], 0, 0, 0);
          acc[i][nt] = __builtin_amdgcn_mfma_f32_16x16x32_bf16(Ab, Bh[1][nt], acc[i][nt], 0, 0, 0);
        }
      }
    }

    #pragma unroll
    for (int i = 0; i < TPW; ++i) {
      const int T = t0 + i;
      #pragma unroll
      for (int nt = 0; nt < 4; ++nt) {
        #pragma unroll
        for (int reg = 0; reg < 4; ++reg) {
          const int row2 = kgrp*4 + reg;
          float v = fast_tanh(acc[i][nt][reg]);
          v = (row2 <= 8) ? v : 0.f;
          const int rr  = T*16 + row2;
          const int col = nt*16 + l15;
          Hs[rr*64 + ((((col >> 3) ^ (row2 & 7))) << 3) + (col & 7)] = f2bs(v);
        }
      }
    }
  }

  // ================= head: per-graph [16x64]@[64x16], scatter stores =================
  {
    short8 H0 = *(const short8*)&g_bfragH[lane*8];
    short8 H1 = *(const short8*)&g_bfragH[512 + lane*8];
    const int p  = l15 >> 1;
    const int oc = l15 & 1;
    const float bh = bhead[l15];                 // = bhead[p*2 + oc]
    const int trow = p + 1;                      // head reads node p+1
    const bool mykg = ((trow >> 2) == kgrp);
    const int treg = trow & 3;

    #pragma unroll
    for (int i = 0; i < TPW; ++i) {
      const int T = t0 + i;
      const int row = T*16 + l15;
      short8 A0 = *(const short8*)&Hs[row*64 + (((0 + kgrp) ^ (l15 & 7)) << 3)];
      short8 A1 = *(const short8*)&Hs[row*64 + (((4 + kgrp) ^ (l15 & 7)) << 3)];
      f32x4 acc = (f32x4){bh, bh, bh, bh};
      acc = __builtin_amdgcn_mfma_f32_16x16x32_bf16(A0, H0, acc, 0, 0, 0);
      acc = __builtin_amdgcn_mfma_f32_16x16x32_bf16(A1, H1, acc, 0, 0, 0);
      float val = (treg & 2) ? ((treg & 1) ? acc[3] : acc[2])
                             : ((treg & 1) ? acc[1] : acc[0]);
      float tv = val + 0.5413248546129181f;      // log(expm1(1))
      float e  = __expf(tv);
      float sp = (tv > 15.f) ? tv : __logf(1.f + e);
      sp = fmaxf(sp, 1e-4f);
      float res = oc ? sp : val;
      if (mykg) {
        const long long gg = (long long)blockIdx.x*GPB + T;
        out[(oc ? OUT_HALF : 0) + gg*8 + p] = res;
      }
    }
  }
}

extern "C" void kernel_launch(void* const* d_in, const int* in_sizes, int n_in,
                              void* d_out, int out_size, void* d_ws, size_t ws_size,
                              hipStream_t stream) {
  const float* x       = (const float*)d_in[0];
  // d_in[1] = edge_index: full 9-clique structure is compile-time, unused
  const float* W_in    = (const float*)d_in[2];
  const float* b_in    = (const float*)d_in[3];
  const float* W1_rel  = (const float*)d_in[4];
  const float* b1      = (const float*)d_in[5];
  const float* W1_root = (const float*)d_in[6];
  const float* W2_rel  = (const float*)d_in[7];
  const float* b2      = (const float*)d_in[8];
  const float* W2_root = (const float*)d_in[9];
  const float* Whead   = (const float*)d_in[10];
  const float* bhead   = (const float*)d_in[11];
  float* out = (float*)d_out;

  hipLaunchKernelGGL(prep_kernel, dim3(18), dim3(TPB), 0, stream,
                     W_in, b_in, W1_rel, b1, W1_root, W2_rel, W2_root, Whead);
  hipLaunchKernelGGL(fused_kernel, dim3(NBLK), dim3(TPB), 0, stream,
                     x, b2, bhead, out);
}